// Round 4
// baseline (247.548 us; speedup 1.0000x reference)
//
#include <hip/hip_runtime.h>

// CortexNetwork: aff + 0.9*exc - 0.9*inh, relu, broadcast over C.
// R3 post-mortem: nt loads beat L1-MSHR cap (101 -> <62us). Fill kernels show
// 6.9 TB/s achievable; FETCH=132MB of 263MB footprint (half L3-resident).
// R4: SPLIT=2, flatten all 16 lateral rows into one stream with 8-deep
// batched nt loads; per-row coeff (+-0.9*prev) and row base pointers in LDS;
// afferent flattened over all 256 threads with 5-deep batching.

constexpr int C   = 16;
constexpr int GX  = 36;
constexpr int GY  = 36;
constexpr int RF  = 24;
constexpr int IMG = 64;
constexpr int GG  = GX * GY;   // 1296
constexpr int RR  = RF * RF;   // 576
constexpr int SPLIT = 2;
constexpr int CPB   = C / SPLIT;   // 8 channels per block

typedef float f4 __attribute__((ext_vector_type(4)));

__global__ __launch_bounds__(256)
void cortex_phase1(const float* __restrict__ x,
                   const float* __restrict__ prev,
                   const float* __restrict__ affW,
                   const float* __restrict__ exW,
                   const float* __restrict__ inW,
                   const int*   __restrict__ rx,
                   const int*   __restrict__ ry,
                   float* __restrict__ partial)
{
    const int bid  = blockIdx.x;
    const int ij   = bid % GG;
    const int half = bid / GG;
    const int cs   = half * CPB;
    const int i = ij / GY;
    const int j = ij - i * GY;
    const unsigned t = threadIdx.x;

    const int rxi = rx[i];
    const int ryj = ry[j];

    // Per-row coefficient and base pointer for the 16 lateral rows
    // (row r: channel cs + (r>>1), tensor = r&1 ? inW : exW).
    __shared__ float        s_co[2 * CPB];
    __shared__ const float* s_rp[2 * CPB];
    if (t < 2 * CPB) {
        const int c = cs + (int)(t >> 1);
        s_co[t] = prev[c * GG + ij] * ((t & 1u) ? -0.9f : 0.9f);
        const float* base = (t & 1u) ? inW : exW;
        s_rp[t] = base + ((size_t)c * GG + ij) * (size_t)GG;
    }
    __syncthreads();

    float acc = 0.0f;

    // ---- Afferent: CPB*RR/4 = 1152 f4, 256 threads, 5-deep batch ----
    {
        constexpr unsigned NAF = CPB * RR / 4;   // 1152
        f4 w[5];
        #pragma unroll
        for (int m = 0; m < 5; ++m) {
            unsigned k = t + m * 256u;
            if (k >= NAF) k = 0u;                // safe dup load, skipped below
            const unsigned cl  = k / 144u;
            const unsigned col = k - cl * 144u;
            w[m] = __builtin_nontemporal_load(
                (const f4*)(affW + ((size_t)(cs + cl) * GG + ij) * RR) + col);
        }
        #pragma unroll
        for (int m = 0; m < 5; ++m) {
            const unsigned k = t + m * 256u;
            if (k >= NAF) continue;
            const unsigned cl  = k / 144u;
            const unsigned col = k - cl * 144u;
            const unsigned u   = col / 6u;
            const unsigned v0  = (col - u * 6u) * 4u;
            const float* xp = x + (((cs + cl) * IMG + rxi + u) * IMG + ryj + v0);
            acc = fmaf(w[m].x, xp[0], acc);
            acc = fmaf(w[m].y, xp[1], acc);
            acc = fmaf(w[m].z, xp[2], acc);
            acc = fmaf(w[m].w, xp[3], acc);
        }
    }

    // ---- Lateral: 16 rows x 324 f4 = 5184 f4, 8-deep batched nt loads ----
    {
        constexpr unsigned NLAT = 2 * CPB * (GG / 4);   // 5184
        for (unsigned base = 0; base < NLAT; base += 8 * 256) {
            f4    v[8];
            float cf[8];
            #pragma unroll
            for (int m = 0; m < 8; ++m) {
                unsigned k = base + m * 256u + t;
                if (k >= NLAT) k = 0u;           // safe dup load, masked by cf=0
                const unsigned r   = k / 324u;
                const unsigned col = k - r * 324u;
                v[m]  = __builtin_nontemporal_load((const f4*)s_rp[r] + col);
                cf[m] = s_co[r];
            }
            #pragma unroll
            for (int m = 0; m < 8; ++m) {
                const unsigned k = base + m * 256u + t;
                const float cfm = (k < NLAT) ? cf[m] : 0.0f;
                acc = fmaf(cfm, (v[m].x + v[m].y) + (v[m].z + v[m].w), acc);
            }
        }
    }

    // ---- Block reduction ----
    for (int off = 32; off > 0; off >>= 1)
        acc += __shfl_down(acc, off, 64);

    __shared__ float sred[4];
    const int wave = t >> 6;
    const int lane = t & 63;
    if (lane == 0) sred[wave] = acc;
    __syncthreads();
    if (t == 0)
        partial[half * GG + ij] = sred[0] + sred[1] + sred[2] + sred[3];
}

__global__ __launch_bounds__(256)
void cortex_phase2(const float* __restrict__ partial, float* __restrict__ out)
{
    const int ij = blockIdx.x * blockDim.x + threadIdx.x;
    if (ij < GG) {
        const float tot = partial[ij] + partial[GG + ij];
        const float a = fmaxf(tot, 0.0f);
        #pragma unroll
        for (int c = 0; c < C; ++c)
            out[c * GG + ij] = a;
    }
}

extern "C" void kernel_launch(void* const* d_in, const int* in_sizes, int n_in,
                              void* d_out, int out_size, void* d_ws, size_t ws_size,
                              hipStream_t stream) {
    const float* x     = (const float*)d_in[0];
    const float* prev  = (const float*)d_in[1];
    const float* affW  = (const float*)d_in[2];
    const float* exW   = (const float*)d_in[3];
    const float* inW   = (const float*)d_in[4];
    const int*   rx    = (const int*)d_in[5];
    const int*   ry    = (const int*)d_in[6];
    float* out     = (float*)d_out;
    float* partial = (float*)d_ws;   // SPLIT * GG floats

    cortex_phase1<<<GG * SPLIT, 256, 0, stream>>>(x, prev, affW, exW, inW, rx, ry, partial);
    cortex_phase2<<<(GG + 255) / 256, 256, 0, stream>>>(partial, out);
}

// Round 5
// 247.020 us; speedup vs baseline: 1.0021x; 1.0021x over previous
//
#include <hip/hip_runtime.h>

// CortexNetwork: aff + 0.9*exc - 0.9*inh, relu, broadcast over C.
// R3: nt loads fixed L1-MSHR cap. R4: deep batching neutral -> MLP not the
// limiter. R5: single fused kernel, one block per (i,j), 1024 thr = 16 waves.
// Each wave owns whole lateral rows (row base + coeff wave-uniform -> SGPR
// addressing, no LDS pointer chase, no per-lane masks except row tail).
// Phase2 folded into the epilogue (threads 0..15 write the 16 channels).

constexpr int C   = 16;
constexpr int GX  = 36;
constexpr int GY  = 36;
constexpr int RF  = 24;
constexpr int IMG = 64;
constexpr int GG  = GX * GY;   // 1296
constexpr int RR  = RF * RF;   // 576

typedef float f4 __attribute__((ext_vector_type(4)));

__global__ __launch_bounds__(1024)
void cortex_fused(const float* __restrict__ x,
                  const float* __restrict__ prev,
                  const float* __restrict__ affW,
                  const float* __restrict__ exW,
                  const float* __restrict__ inW,
                  const int*   __restrict__ rx,
                  const int*   __restrict__ ry,
                  float* __restrict__ out)
{
    const int ij = blockIdx.x;
    const int i = ij / GY;
    const int j = ij - i * GY;
    const unsigned t    = threadIdx.x;
    const unsigned wave = t >> 6;
    const unsigned lane = t & 63u;

    const int rxi = rx[i];
    const int ryj = ry[j];

    float acc = 0.0f;

    // ---- Afferent: C*RR/4 = 2304 f4 over 1024 threads (2.25 each) ----
    {
        constexpr unsigned NAF = C * RR / 4;   // 2304
        const unsigned k0 = t;
        const unsigned k1 = t + 1024u;
        const bool has2   = t < (NAF - 2048u); // t < 256
        const unsigned k2 = has2 ? (t + 2048u) : 0u;

        const unsigned cl0 = k0 / 144u, co0 = k0 - cl0 * 144u;
        const unsigned cl1 = k1 / 144u, co1 = k1 - cl1 * 144u;
        const unsigned cl2 = k2 / 144u, co2 = k2 - cl2 * 144u;

        const f4 w0 = __builtin_nontemporal_load(
            (const f4*)(affW + ((size_t)cl0 * GG + ij) * RR) + co0);
        const f4 w1 = __builtin_nontemporal_load(
            (const f4*)(affW + ((size_t)cl1 * GG + ij) * RR) + co1);
        f4 w2 = (f4)(0.0f);
        if (has2)
            w2 = __builtin_nontemporal_load(
                (const f4*)(affW + ((size_t)cl2 * GG + ij) * RR) + co2);

        const unsigned u0 = co0 / 6u, v0 = (co0 - u0 * 6u) * 4u;
        const unsigned u1 = co1 / 6u, v1 = (co1 - u1 * 6u) * 4u;
        const unsigned u2 = co2 / 6u, v2 = (co2 - u2 * 6u) * 4u;

        const float* xp0 = x + ((cl0 * IMG + rxi + u0) * IMG + ryj + v0);
        const float* xp1 = x + ((cl1 * IMG + rxi + u1) * IMG + ryj + v1);
        const float* xp2 = x + ((cl2 * IMG + rxi + u2) * IMG + ryj + v2);

        acc = fmaf(w0.x, xp0[0], acc); acc = fmaf(w0.y, xp0[1], acc);
        acc = fmaf(w0.z, xp0[2], acc); acc = fmaf(w0.w, xp0[3], acc);
        acc = fmaf(w1.x, xp1[0], acc); acc = fmaf(w1.y, xp1[1], acc);
        acc = fmaf(w1.z, xp1[2], acc); acc = fmaf(w1.w, xp1[3], acc);
        if (has2) {
            acc = fmaf(w2.x, xp2[0], acc); acc = fmaf(w2.y, xp2[1], acc);
            acc = fmaf(w2.z, xp2[2], acc); acc = fmaf(w2.w, xp2[3], acc);
        }
    }

    // ---- Lateral: 32 rows (c, ex/in) x 324 f4; wave w owns rows w, w+16 ----
    // Row base and coeff are wave-uniform -> SGPR-based addressing.
    #pragma unroll
    for (int rr = 0; rr < 2; ++rr) {
        const int r = (int)wave + rr * 16;
        const int c = r >> 1;
        const float* tb = (r & 1) ? inW : exW;
        const f4* row = (const f4*)(tb + ((size_t)c * GG + ij) * (size_t)GG);
        const float coeff = prev[c * GG + ij] * ((r & 1) ? -0.9f : 0.9f);

        f4 v[6];
        #pragma unroll
        for (int m = 0; m < 5; ++m)
            v[m] = __builtin_nontemporal_load(row + lane + m * 64u);
        v[5] = (f4)(0.0f);
        if (lane < 4u)                         // row tail: 324 = 5*64 + 4
            v[5] = __builtin_nontemporal_load(row + 320u + lane);

        float s = 0.0f;
        #pragma unroll
        for (int m = 0; m < 6; ++m)
            s += (v[m].x + v[m].y) + (v[m].z + v[m].w);
        acc = fmaf(coeff, s, acc);
    }

    // ---- Reduction: wave shuffle, then 16 partials in LDS ----
    for (int off = 32; off > 0; off >>= 1)
        acc += __shfl_down(acc, off, 64);

    __shared__ float sred[16];
    __shared__ float s_act;
    if (lane == 0) sred[wave] = acc;
    __syncthreads();
    if (t == 0) {
        float tot = 0.0f;
        #pragma unroll
        for (int w = 0; w < 16; ++w) tot += sred[w];
        s_act = fmaxf(tot, 0.0f);
    }
    __syncthreads();

    if (t < C)
        out[t * GG + ij] = s_act;
}

extern "C" void kernel_launch(void* const* d_in, const int* in_sizes, int n_in,
                              void* d_out, int out_size, void* d_ws, size_t ws_size,
                              hipStream_t stream) {
    const float* x     = (const float*)d_in[0];
    const float* prev  = (const float*)d_in[1];
    const float* affW  = (const float*)d_in[2];
    const float* exW   = (const float*)d_in[3];
    const float* inW   = (const float*)d_in[4];
    const int*   rx    = (const int*)d_in[5];
    const int*   ry    = (const int*)d_in[6];
    float* out = (float*)d_out;

    cortex_fused<<<GG, 1024, 0, stream>>>(x, prev, affW, exW, inW, rx, ry, out);
}